// Round 3
// 185.672 us; speedup vs baseline: 1.1138x; 1.1138x over previous
//
#include <hip/hip_runtime.h>
#include <math.h>

#define BB 8
#define VV 2
#define HH 1024
#define WW 1024
#define NPTS 131072
#define IMG (HH*WW)
#define FUSED (VV*BB*IMG)   // 16777216

#define NSOLVE (NPTS/256)      // 512 solve blocks
#define NCLEAR ((2*NPTS)/256)  // 1024 clear blocks
#define NCOPY  (FUSED/4/256)   // 16384 copy blocks (float4)

// native clang vector type: __builtin_nontemporal_store rejects HIP_vector_type
typedef float f32x4 __attribute__((ext_vector_type(4)));

// ---- workspace layout (bytes)
#define OFF_Z    0u                          // float[2*NPTS] (z, 0 = invalid)
#define OFF_PIX  (8u*NPTS)                   // int[2*NPTS]
#define OFF_RED  (16u*NPTS)                  // int[NSOLVE*40] block slots: 16 near,16 far,8 has
#define OFF_WIN  (OFF_RED + 0x20000u)        // int[FUSED] = 64 MiB
#define WS_NEED  ((size_t)OFF_WIN + 4ull*(size_t)FUSED)

__device__ __forceinline__ int clampi(int v, int lo, int hi) {
    return v < lo ? lo : (v > hi ? hi : v);
}

// per-(b,v) prep (t = 0..15): P = (intr*rowscale) @ inv(E)[:3,:] -> sD[t*12..],
// e2 = inv(E)[2,:] -> sD[192 + t*4..].
// E is a RIGID transform by construction (R|t; 0 0 0 1) -> closed-form inverse
// [R^T | -R^T t]. All static indexing -> registers only. (The old Gauss-Jordan
// with runtime pivot indices forced the 4x8 f64 matrix into scratch: ~dozens of
// ~500cy scratch round-trips serializing every solve block's prologue.)
__device__ __forceinline__ void prep_one(int t, const float* __restrict__ intr,
                                         const float* __restrict__ extr, double* sD) {
    const float* E = extr + t * 16;
    double R[3][3], tr[3];
#pragma unroll
    for (int i = 0; i < 3; i++) {
#pragma unroll
        for (int j = 0; j < 3; j++) R[i][j] = (double)E[i * 4 + j];
        tr[i] = (double)E[i * 4 + 3];
    }
    double inv[3][4];   // rows 0..2 of inv(E); row 3 is (0,0,0,1)
#pragma unroll
    for (int i = 0; i < 3; i++) {
#pragma unroll
        for (int j = 0; j < 3; j++) inv[i][j] = R[j][i];
        inv[i][3] = -(R[0][i] * tr[0] + R[1][i] * tr[1] + R[2][i] * tr[2]);
    }
    const float* K = intr + t * 9;
    double rs[3] = {(double)WW, (double)HH, 1.0};
#pragma unroll
    for (int i = 0; i < 3; i++)
#pragma unroll
        for (int k = 0; k < 4; k++) {
            double s = 0.0;
#pragma unroll
            for (int j = 0; j < 3; j++) s += (double)K[i * 3 + j] * rs[i] * inv[j][k];
            sD[t * 12 + i * 4 + k] = s;
        }
#pragma unroll
    for (int k = 0; k < 4; k++) sD[192 + t * 4 + k] = inv[2][k];
}

// K1: fused. blocks [0,NSOLVE): per-point Jacobi solve (stores z,pix + block near/far slot);
//            [NSOLVE, NSOLVE+NCLEAR): clear winner cells; rest: bulk copy disps->out.
// Solve blocks placed FIRST so copy waves fill their latency bubbles.
template <int DEDUP>
__global__ __launch_bounds__(256) void mega_kernel(
        const f32x4* __restrict__ src, f32x4* __restrict__ dst,
        const float2* __restrict__ mk0, const float2* __restrict__ mk1,
        const int* __restrict__ mbids,
        const float* __restrict__ intr, const float* __restrict__ extr,
        const float* __restrict__ disps,
        float* __restrict__ out, char* __restrict__ ws) {
    int b = blockIdx.x, t = threadIdx.x;

    if (b >= NSOLVE + NCLEAR) {            // ---- copy role
        int i = (b - NSOLVE - NCLEAR) * 256 + t;
        // non-temporal store: don't let the 64 MB out-copy evict disps from L2/LLC
        // (resolve_kernel re-reads disps at scattered winner pixels next launch)
        f32x4 v = src[i];
        __builtin_nontemporal_store(v, &dst[i]);
        return;
    }
    if (b >= NSOLVE) {                     // ---- clear-winner role
        if (DEDUP) {
            int id = (b - NSOLVE) * 256 + t;
            int n = id >> 1, v = id & 1;
            const float2* mk = v ? mk1 : mk0;
            float2 q = mk[n];
            int xi = clampi((int)q.x, 0, WW - 1);
            int yi = clampi((int)q.y, 0, HH - 1);
            int bid = mbids[n];
            ((int*)(ws + OFF_WIN))[(v * BB + bid) * IMG + yi * WW + xi] = -1;
        }
        return;
    }

    // ---- solve role
    __shared__ double sD[256];             // 192 P doubles + 64 e2 doubles
    __shared__ int nearB[16], farB[16], hasB[8];
    if (t < 16) {
        prep_one(t, intr, extr, sD);
        nearB[t] = 0x7F800000;             // +inf bits
        farB[t]  = 0;                      // 0.0f bits
        if (t < 8) hasB[t] = 0;
    }
    __syncthreads();

    int n = b * 256 + t;
    float* zarr   = (float*)(ws + OFF_Z);
    int*   pixarr = (int*)(ws + OFF_PIX);

    int bid = mbids[n];
    float2 q0 = mk0[n], q1 = mk1[n];
    float xf[2] = {q0.x, q1.x};
    float yf[2] = {q0.y, q1.y};

    // M = A^T A  (mconf is a uniform positive scale of A -> no effect on eigvecs)
    double M[4][4];
#pragma unroll
    for (int i = 0; i < 4; i++)
#pragma unroll
        for (int j = 0; j < 4; j++) M[i][j] = 0.0;
#pragma unroll
    for (int v = 0; v < 2; v++) {
        const double* P = sD + (bid * VV + v) * 12;
        double xx = (double)xf[v], yy = (double)yf[v];
        double r0[4], r1[4];
#pragma unroll
        for (int j = 0; j < 4; j++) {
            r0[j] = xx * P[8 + j] - P[j];
            r1[j] = yy * P[8 + j] - P[4 + j];
        }
#pragma unroll
        for (int i = 0; i < 4; i++)
#pragma unroll
            for (int j = 0; j < 4; j++) M[i][j] += r0[i] * r0[j] + r1[i] * r1[j];
    }

    // cyclic Jacobi, f64 (verified: absmax 32)
    double Vm[4][4] = {{1, 0, 0, 0}, {0, 1, 0, 0}, {0, 0, 1, 0}, {0, 0, 0, 1}};
    for (int sweep = 0; sweep < 8; ++sweep) {
        double off = fabs(M[0][1]) + fabs(M[0][2]) + fabs(M[0][3]) +
                     fabs(M[1][2]) + fabs(M[1][3]) + fabs(M[2][3]);
        double dia = fabs(M[0][0]) + fabs(M[1][1]) + fabs(M[2][2]) + fabs(M[3][3]);
        if (off <= 1e-13 * dia) break;
#pragma unroll
        for (int p = 0; p < 3; p++) {
#pragma unroll
            for (int q = p + 1; q < 4; q++) {
                double apq = M[p][q];
                if (fabs(apq) < 1e-300) continue;
                double tau = (M[q][q] - M[p][p]) / (2.0 * apq);
                double rt  = sqrt(1.0 + tau * tau);
                double t_  = (tau >= 0.0) ? 1.0 / (tau + rt) : 1.0 / (tau - rt);
                double c = 1.0 / sqrt(1.0 + t_ * t_);
                double s = t_ * c;
#pragma unroll
                for (int k = 0; k < 4; k++) {
                    double mp = M[k][p], mq = M[k][q];
                    M[k][p] = c * mp - s * mq;
                    M[k][q] = s * mp + c * mq;
                }
#pragma unroll
                for (int k = 0; k < 4; k++) {
                    double mp = M[p][k], mq = M[q][k];
                    M[p][k] = c * mp - s * mq;
                    M[q][k] = s * mp + c * mq;
                }
#pragma unroll
                for (int k = 0; k < 4; k++) {
                    double vp = Vm[k][p], vq = Vm[k][q];
                    Vm[k][p] = c * vp - s * vq;
                    Vm[k][q] = s * vp + c * vq;
                }
            }
        }
    }
    int jmin = 0; double dmin = M[0][0];
    if (M[1][1] < dmin) { dmin = M[1][1]; jmin = 1; }
    if (M[2][2] < dmin) { dmin = M[2][2]; jmin = 2; }
    if (M[3][3] < dmin) { dmin = M[3][3]; jmin = 3; }

    double ev[4];
#pragma unroll
    for (int i = 0; i < 4; i++) {
        double a01 = (jmin == 0) ? Vm[i][0] : Vm[i][1];
        double a23 = (jmin == 2) ? Vm[i][2] : Vm[i][3];
        ev[i] = (jmin < 2) ? a01 : a23;
    }
    double iw  = 1.0 / ev[3];
    double pwx = ev[0] * iw, pwy = ev[1] * iw, pwz = ev[2] * iw;

    double z[2];
#pragma unroll
    for (int v = 0; v < 2; v++) {
        const double* e = sD + 192 + (bid * VV + v) * 4;
        z[v] = e[0] * pwx + e[1] * pwy + e[2] * pwz + e[3];
    }
    bool valid = (z[0] > 0.0) && (z[0] < 500.0) && (z[1] > 0.0) && (z[1] < 500.0);

    // block-local near/far/has via LDS (no global atomics, no init ordering)
    unsigned long long vb = __ballot(valid);
    int bidFirst = __shfl(bid, 0);
    int bidLast  = __shfl(bid, 63);
    if (bidFirst == bidLast) {
        if (vb != 0ULL) {
            float zn[2], zf[2];
#pragma unroll
            for (int v = 0; v < 2; v++) {
                zn[v] = valid ? (float)z[v] : INFINITY;
                zf[v] = valid ? (float)z[v] : -1.0f;
            }
#pragma unroll
            for (int off = 32; off > 0; off >>= 1) {
#pragma unroll
                for (int v = 0; v < 2; v++) {
                    zn[v] = fminf(zn[v], __shfl_down(zn[v], off));
                    zf[v] = fmaxf(zf[v], __shfl_down(zf[v], off));
                }
            }
            if ((t & 63) == 0) {
#pragma unroll
                for (int v = 0; v < 2; v++) {
                    atomicMin(&nearB[bid * VV + v], __float_as_int(zn[v]));
                    atomicMax(&farB[bid * VV + v],  __float_as_int(zf[v]));
                }
                atomicOr(&hasB[bid], 1);
            }
        }
    } else if (valid) {        // rare boundary wave
#pragma unroll
        for (int v = 0; v < 2; v++) {
            int fb = __float_as_int((float)z[v]);
            atomicMin(&nearB[bid * VV + v], fb);
            atomicMax(&farB[bid * VV + v],  fb);
        }
        atomicOr(&hasB[bid], 1);
    }

#pragma unroll
    for (int v = 0; v < 2; v++) {
        int xi = clampi((int)xf[v], 0, WW - 1);
        int yi = clampi((int)yf[v], 0, HH - 1);
        int pix = (v * BB + bid) * IMG + yi * WW + xi;
        if (DEDUP) {
            zarr[2 * n + v]   = valid ? (float)z[v] : 0.0f;
            pixarr[2 * n + v] = pix;
        } else {
            float cost = disps[pix];
            float val = valid ? (float)(0.5 * (1.0 / z[v]) + 0.5 * (double)cost) : cost;
            out[pix] = val;    // fallback: nondeterministic duplicate order
        }
    }

    __syncthreads();
    int* red = (int*)(ws + OFF_RED) + b * 40;
    if (t < 16) {
        red[t]      = nearB[t];
        red[16 + t] = farB[t];
        if (t < 8) red[32 + t] = hasB[t];
    }
}

// K2: vote (runs after clear is complete; kernel boundary provides the ordering)
__global__ __launch_bounds__(256) void vote_kernel(char* __restrict__ ws) {
    int id = blockIdx.x * 256 + threadIdx.x;   // grid exactly NCLEAR
    const int* pixarr = (const int*)(ws + OFF_PIX);
    int* winner = (int*)(ws + OFF_WIN);
    atomicMax(winner + pixarr[id], id >> 1);   // last-update-wins == max n
}

// K3: winner writes its val; block 0 also reduces the per-block near/far/has slots
// (wave-parallel: 4 waves x 10 cells, lanes stride the 512 solve-block slots --
//  replaces the old serial 512-iteration loop on 32 threads).
__global__ __launch_bounds__(256) void resolve_kernel(const float* __restrict__ disps,
                                                      float* __restrict__ out,
                                                      const char* __restrict__ ws,
                                                      int dedup) {
    int id = blockIdx.x * 256 + threadIdx.x;
    if (dedup) {
        const float* zarr   = (const float*)(ws + OFF_Z);
        const int*   pixarr = (const int*)(ws + OFF_PIX);
        const int*   winner = (const int*)(ws + OFF_WIN);
        int   pix = pixarr[id];
        float zf  = zarr[id];
        if (winner[pix] == (id >> 1) && zf > 0.0f) {
            float cost = disps[pix];
            out[pix] = (float)(0.5 * (1.0 / (double)zf) + 0.5 * (double)cost);
        }
    }
    if (blockIdx.x == 0) {
        __shared__ int redLds[40];
        int t = threadIdx.x;
        const int* red = (const int*)(ws + OFF_RED);
        int w = t >> 6, lane = t & 63;
        for (int c = w; c < 40; c += 4) {          // 10 cells per wave
            int acc = (c < 16) ? 0x7F800000 : 0;
            for (int s = lane; s < NSOLVE; s += 64) {
                int vv = red[s * 40 + c];
                acc = (c < 16) ? min(acc, vv) : (c < 32 ? max(acc, vv) : (acc | vv));
            }
#pragma unroll
            for (int off = 32; off > 0; off >>= 1) {
                int o = __shfl_down(acc, off);
                acc = (c < 16) ? min(acc, o) : (c < 32 ? max(acc, o) : (acc | o));
            }
            if (lane == 0) redLds[c] = acc;
        }
        __syncthreads();
        if (t < 16) {
            int hv = redLds[32 + (t >> 1)];
            out[FUSED + t]               = hv ? __int_as_float(redLds[t])      : 0.0f;   // near
            out[FUSED + BB * VV + t]     = hv ? __int_as_float(redLds[16 + t]) : 500.0f; // far
            out[FUSED + 2 * BB * VV + t] = hv ? 1.0f : 0.0f;                             // flag
        }
    }
}

extern "C" void kernel_launch(void* const* d_in, const int* in_sizes, int n_in,
                              void* d_out, int out_size, void* d_ws, size_t ws_size,
                              hipStream_t stream) {
    const float* mk0   = (const float*)d_in[0];
    const float* mk1   = (const float*)d_in[1];
    // d_in[2] = mconf: uniform positive scale of A, no effect on null vector -> unused
    const int*   mbids = (const int*)d_in[3];
    const float* intr  = (const float*)d_in[4];
    const float* extr  = (const float*)d_in[5];
    const float* disps = (const float*)d_in[6];
    float* out = (float*)d_out;
    char*  ws  = (char*)d_ws;

    bool dedup = (ws_size >= WS_NEED);
    dim3 grid(NSOLVE + NCLEAR + NCOPY);

    if (dedup) {
        mega_kernel<1><<<grid, 256, 0, stream>>>(
            (const f32x4*)disps, (f32x4*)out, (const float2*)mk0, (const float2*)mk1,
            mbids, intr, extr, disps, out, ws);
        vote_kernel<<<NCLEAR, 256, 0, stream>>>(ws);
        resolve_kernel<<<NCLEAR, 256, 0, stream>>>(disps, out, ws, 1);
    } else {
        mega_kernel<0><<<grid, 256, 0, stream>>>(
            (const f32x4*)disps, (f32x4*)out, (const float2*)mk0, (const float2*)mk1,
            mbids, intr, extr, disps, out, ws);
        resolve_kernel<<<1, 256, 0, stream>>>(disps, out, ws, 0);
    }
}

// Round 4
// 183.985 us; speedup vs baseline: 1.1241x; 1.0092x over previous
//
#include <hip/hip_runtime.h>
#include <math.h>

#define BB 8
#define VV 2
#define HH 1024
#define WW 1024
#define NPTS 131072
#define IMG (HH*WW)
#define FUSED (VV*BB*IMG)   // 16777216

#define NSOLVE (NPTS/256)      // 512 solve blocks
#define NCOPY  (FUSED/4/256)   // 16384 copy blocks (float4)

// native clang vector type: __builtin_nontemporal_store rejects HIP_vector_type
typedef float f32x4 __attribute__((ext_vector_type(4)));

// ---- workspace layout (bytes)
#define OFF_VAL  0u                          // float[2*NPTS] fused val (0 = invalid -> no write)
#define OFF_PIX  (8u*NPTS)                   // int[2*NPTS]
#define OFF_RED  (16u*NPTS)                  // int[NSOLVE*40] block slots: 16 near,16 far,8 has
#define OFF_WIN  (OFF_RED + 0x20000u)        // int[FUSED] = 64 MiB
#define WS_NEED  ((size_t)OFF_WIN + 4ull*(size_t)FUSED)

__device__ __forceinline__ int clampi(int v, int lo, int hi) {
    return v < lo ? lo : (v > hi ? hi : v);
}

// per-(b,v) prep (t = 0..15): P = (intr*rowscale) @ inv(E)[:3,:] -> sD[t*12..],
// e2 = inv(E)[2,:] -> sD[192 + t*4..].
// E is RIGID (R|t; 0 0 0 1) -> closed-form inverse [R^T | -R^T t]; static
// indexing only -> registers (runtime-pivot Gauss-Jordan went to scratch).
__device__ __forceinline__ void prep_one(int t, const float* __restrict__ intr,
                                         const float* __restrict__ extr, double* sD) {
    const float* E = extr + t * 16;
    double R[3][3], tr[3];
#pragma unroll
    for (int i = 0; i < 3; i++) {
#pragma unroll
        for (int j = 0; j < 3; j++) R[i][j] = (double)E[i * 4 + j];
        tr[i] = (double)E[i * 4 + 3];
    }
    double inv[3][4];   // rows 0..2 of inv(E); row 3 is (0,0,0,1)
#pragma unroll
    for (int i = 0; i < 3; i++) {
#pragma unroll
        for (int j = 0; j < 3; j++) inv[i][j] = R[j][i];
        inv[i][3] = -(R[0][i] * tr[0] + R[1][i] * tr[1] + R[2][i] * tr[2]);
    }
    const float* K = intr + t * 9;
    double rs[3] = {(double)WW, (double)HH, 1.0};
#pragma unroll
    for (int i = 0; i < 3; i++)
#pragma unroll
        for (int k = 0; k < 4; k++) {
            double s = 0.0;
#pragma unroll
            for (int j = 0; j < 3; j++) s += (double)K[i * 3 + j] * rs[i] * inv[j][k];
            sD[t * 12 + i * 4 + k] = s;
        }
#pragma unroll
    for (int k = 0; k < 4; k++) sD[192 + t * 4 + k] = inv[2][k];
}

// K1: blocks [0,NSOLVE): per-point solve. Computes z, valid, gathers cost=disps[pix]
//     (latency hidden under Jacobi), stores final val+pix, clears own winner cells,
//     writes per-block near/far/has slots. blocks >= NSOLVE: bulk copy disps->out.
template <int DEDUP>
__global__ __launch_bounds__(256) void mega_kernel(
        const f32x4* __restrict__ src, f32x4* __restrict__ dst,
        const float2* __restrict__ mk0, const float2* __restrict__ mk1,
        const int* __restrict__ mbids,
        const float* __restrict__ intr, const float* __restrict__ extr,
        const float* __restrict__ disps,
        float* __restrict__ out, char* __restrict__ ws) {
    int b = blockIdx.x, t = threadIdx.x;

    if (b >= NSOLVE) {                     // ---- copy role
        int i = (b - NSOLVE) * 256 + t;
        // non-temporal store: don't let the 64 MB out-copy evict disps from L2/LLC
        f32x4 v = src[i];
        __builtin_nontemporal_store(v, &dst[i]);
        return;
    }

    // ---- solve role
    __shared__ double sD[256];             // 192 P doubles + 64 e2 doubles
    __shared__ int nearB[16], farB[16], hasB[8];
    if (t < 16) {
        prep_one(t, intr, extr, sD);
        nearB[t] = 0x7F800000;             // +inf bits
        farB[t]  = 0;                      // 0.0f bits
        if (t < 8) hasB[t] = 0;
    }
    __syncthreads();

    int n = b * 256 + t;
    float* valarr = (float*)(ws + OFF_VAL);
    int*   pixarr = (int*)(ws + OFF_PIX);
    int*   winner = (int*)(ws + OFF_WIN);

    int bid = mbids[n];
    float2 q0 = mk0[n], q1 = mk1[n];
    float xf[2] = {q0.x, q1.x};
    float yf[2] = {q0.y, q1.y};

    // M = A^T A  (mconf is a uniform positive scale of A -> no effect on eigvecs)
    double M[4][4];
#pragma unroll
    for (int i = 0; i < 4; i++)
#pragma unroll
        for (int j = 0; j < 4; j++) M[i][j] = 0.0;
#pragma unroll
    for (int v = 0; v < 2; v++) {
        const double* P = sD + (bid * VV + v) * 12;
        double xx = (double)xf[v], yy = (double)yf[v];
        double r0[4], r1[4];
#pragma unroll
        for (int j = 0; j < 4; j++) {
            r0[j] = xx * P[8 + j] - P[j];
            r1[j] = yy * P[8 + j] - P[4 + j];
        }
#pragma unroll
        for (int i = 0; i < 4; i++)
#pragma unroll
            for (int j = 0; j < 4; j++) M[i][j] += r0[i] * r0[j] + r1[i] * r1[j];
    }

    // cyclic Jacobi, f64 (verified: absmax 32)
    double Vm[4][4] = {{1, 0, 0, 0}, {0, 1, 0, 0}, {0, 0, 1, 0}, {0, 0, 0, 1}};
    for (int sweep = 0; sweep < 8; ++sweep) {
        double off = fabs(M[0][1]) + fabs(M[0][2]) + fabs(M[0][3]) +
                     fabs(M[1][2]) + fabs(M[1][3]) + fabs(M[2][3]);
        double dia = fabs(M[0][0]) + fabs(M[1][1]) + fabs(M[2][2]) + fabs(M[3][3]);
        if (off <= 1e-13 * dia) break;
#pragma unroll
        for (int p = 0; p < 3; p++) {
#pragma unroll
            for (int q = p + 1; q < 4; q++) {
                double apq = M[p][q];
                if (fabs(apq) < 1e-300) continue;
                double tau = (M[q][q] - M[p][p]) / (2.0 * apq);
                double rt  = sqrt(1.0 + tau * tau);
                double t_  = (tau >= 0.0) ? 1.0 / (tau + rt) : 1.0 / (tau - rt);
                double c = 1.0 / sqrt(1.0 + t_ * t_);
                double s = t_ * c;
#pragma unroll
                for (int k = 0; k < 4; k++) {
                    double mp = M[k][p], mq = M[k][q];
                    M[k][p] = c * mp - s * mq;
                    M[k][q] = s * mp + c * mq;
                }
#pragma unroll
                for (int k = 0; k < 4; k++) {
                    double mp = M[p][k], mq = M[q][k];
                    M[p][k] = c * mp - s * mq;
                    M[q][k] = s * mp + c * mq;
                }
#pragma unroll
                for (int k = 0; k < 4; k++) {
                    double vp = Vm[k][p], vq = Vm[k][q];
                    Vm[k][p] = c * vp - s * vq;
                    Vm[k][q] = s * vp + c * vq;
                }
            }
        }
    }
    int jmin = 0; double dmin = M[0][0];
    if (M[1][1] < dmin) { dmin = M[1][1]; jmin = 1; }
    if (M[2][2] < dmin) { dmin = M[2][2]; jmin = 2; }
    if (M[3][3] < dmin) { dmin = M[3][3]; jmin = 3; }

    double ev[4];
#pragma unroll
    for (int i = 0; i < 4; i++) {
        double a01 = (jmin == 0) ? Vm[i][0] : Vm[i][1];
        double a23 = (jmin == 2) ? Vm[i][2] : Vm[i][3];
        ev[i] = (jmin < 2) ? a01 : a23;
    }
    double iw  = 1.0 / ev[3];
    double pwx = ev[0] * iw, pwy = ev[1] * iw, pwz = ev[2] * iw;

    double z[2];
#pragma unroll
    for (int v = 0; v < 2; v++) {
        const double* e = sD + 192 + (bid * VV + v) * 4;
        z[v] = e[0] * pwx + e[1] * pwy + e[2] * pwz + e[3];
    }
    bool valid = (z[0] > 0.0) && (z[0] < 500.0) && (z[1] > 0.0) && (z[1] < 500.0);

    // block-local near/far/has via LDS (no global atomics, no init ordering)
    unsigned long long vb = __ballot(valid);
    int bidFirst = __shfl(bid, 0);
    int bidLast  = __shfl(bid, 63);
    if (bidFirst == bidLast) {
        if (vb != 0ULL) {
            float zn[2], zf[2];
#pragma unroll
            for (int v = 0; v < 2; v++) {
                zn[v] = valid ? (float)z[v] : INFINITY;
                zf[v] = valid ? (float)z[v] : -1.0f;
            }
#pragma unroll
            for (int off = 32; off > 0; off >>= 1) {
#pragma unroll
                for (int v = 0; v < 2; v++) {
                    zn[v] = fminf(zn[v], __shfl_down(zn[v], off));
                    zf[v] = fmaxf(zf[v], __shfl_down(zf[v], off));
                }
            }
            if ((t & 63) == 0) {
#pragma unroll
                for (int v = 0; v < 2; v++) {
                    atomicMin(&nearB[bid * VV + v], __float_as_int(zn[v]));
                    atomicMax(&farB[bid * VV + v],  __float_as_int(zf[v]));
                }
                atomicOr(&hasB[bid], 1);
            }
        }
    } else if (valid) {        // rare boundary wave
#pragma unroll
        for (int v = 0; v < 2; v++) {
            int fb = __float_as_int((float)z[v]);
            atomicMin(&nearB[bid * VV + v], fb);
            atomicMax(&farB[bid * VV + v],  fb);
        }
        atomicOr(&hasB[bid], 1);
    }

#pragma unroll
    for (int v = 0; v < 2; v++) {
        int xi = clampi((int)xf[v], 0, WW - 1);
        int yi = clampi((int)yf[v], 0, HH - 1);
        int pix = (v * BB + bid) * IMG + yi * WW + xi;
        float cost = disps[pix];               // scattered gather, hidden under Jacobi
        if (DEDUP) {
            winner[pix] = 0;                   // clear own winner cell (dup stores benign)
            // val==0 marks "winner writes nothing": invalid writes cost == the
            // copied value (no-op), so skipping the write is equivalent.
            valarr[2 * n + v] = valid ? (float)(0.5 * (1.0 / z[v]) + 0.5 * (double)cost)
                                      : 0.0f;
            pixarr[2 * n + v] = pix;
        } else {
            float val = valid ? (float)(0.5 * (1.0 / z[v]) + 0.5 * (double)cost) : cost;
            out[pix] = val;    // fallback: nondeterministic duplicate order
        }
    }

    __syncthreads();
    int* red = (int*)(ws + OFF_RED) + b * 40;
    if (t < 16) {
        red[t]      = nearB[t];
        red[16 + t] = farB[t];
        if (t < 8) red[32 + t] = hasB[t];
    }
}

// shared near/far/has reduce over the NSOLVE per-block slots (wave-parallel)
__device__ __forceinline__ void reduce_nearfar(const char* __restrict__ ws,
                                               float* __restrict__ out) {
    __shared__ int redLds[40];
    int t = threadIdx.x;
    const int* red = (const int*)(ws + OFF_RED);
    int w = t >> 6, lane = t & 63;
    for (int c = w; c < 40; c += 4) {          // 10 cells per wave
        int acc = (c < 16) ? 0x7F800000 : 0;
        for (int s = lane; s < NSOLVE; s += 64) {
            int vv = red[s * 40 + c];
            acc = (c < 16) ? min(acc, vv) : (c < 32 ? max(acc, vv) : (acc | vv));
        }
#pragma unroll
        for (int off = 32; off > 0; off >>= 1) {
            int o = __shfl_down(acc, off);
            acc = (c < 16) ? min(acc, o) : (c < 32 ? max(acc, o) : (acc | o));
        }
        if (lane == 0) redLds[c] = acc;
    }
    __syncthreads();
    if (t < 16) {
        int hv = redLds[32 + (t >> 1)];
        out[FUSED + t]               = hv ? __int_as_float(redLds[t])      : 0.0f;   // near
        out[FUSED + BB * VV + t]     = hv ? __int_as_float(redLds[16 + t]) : 500.0f; // far
        out[FUSED + 2 * BB * VV + t] = hv ? 1.0f : 0.0f;                             // flag
    }
}

// K2: vote (after K1's clears; kernel boundary orders). 2 votes/thread, int2 loads.
// Block 0 also reduces the near/far/has slots (ready since K1 completed).
__global__ __launch_bounds__(256) void vote_kernel(char* __restrict__ ws,
                                                   float* __restrict__ out) {
    int gid = blockIdx.x * 256 + threadIdx.x;   // grid exactly NSOLVE
    const int2* pix2 = (const int2*)(ws + OFF_PIX);
    int* winner = (int*)(ws + OFF_WIN);
    int2 p = pix2[gid];
    atomicMax(winner + p.x, 2 * gid + 1);       // vote = id+1 (>0); max id == last-wins
    atomicMax(winner + p.y, 2 * gid + 2);
    if (blockIdx.x == 0) reduce_nearfar(ws, out);
}

// K3: winner writes its precomputed val (no gather, no divide).
__global__ __launch_bounds__(256) void resolve_kernel(float* __restrict__ out,
                                                      const char* __restrict__ ws) {
    int gid = blockIdx.x * 256 + threadIdx.x;   // grid exactly NSOLVE
    const int2*   pix2 = (const int2*)(ws + OFF_PIX);
    const float2* val2 = (const float2*)(ws + OFF_VAL);
    const int*    winner = (const int*)(ws + OFF_WIN);
    int2 p = pix2[gid];
    float2 v = val2[gid];
    if (v.x > 0.0f && winner[p.x] == 2 * gid + 1) out[p.x] = v.x;
    if (v.y > 0.0f && winner[p.y] == 2 * gid + 2) out[p.y] = v.y;
}

// fallback-path reduce (1 block)
__global__ __launch_bounds__(256) void reduce_kernel(float* __restrict__ out,
                                                     const char* __restrict__ ws) {
    reduce_nearfar(ws, out);
}

extern "C" void kernel_launch(void* const* d_in, const int* in_sizes, int n_in,
                              void* d_out, int out_size, void* d_ws, size_t ws_size,
                              hipStream_t stream) {
    const float* mk0   = (const float*)d_in[0];
    const float* mk1   = (const float*)d_in[1];
    // d_in[2] = mconf: uniform positive scale of A, no effect on null vector -> unused
    const int*   mbids = (const int*)d_in[3];
    const float* intr  = (const float*)d_in[4];
    const float* extr  = (const float*)d_in[5];
    const float* disps = (const float*)d_in[6];
    float* out = (float*)d_out;
    char*  ws  = (char*)d_ws;

    bool dedup = (ws_size >= WS_NEED);
    dim3 grid(NSOLVE + NCOPY);

    if (dedup) {
        mega_kernel<1><<<grid, 256, 0, stream>>>(
            (const f32x4*)disps, (f32x4*)out, (const float2*)mk0, (const float2*)mk1,
            mbids, intr, extr, disps, out, ws);
        vote_kernel<<<NSOLVE, 256, 0, stream>>>(ws, out);
        resolve_kernel<<<NSOLVE, 256, 0, stream>>>(out, ws);
    } else {
        mega_kernel<0><<<grid, 256, 0, stream>>>(
            (const f32x4*)disps, (f32x4*)out, (const float2*)mk0, (const float2*)mk1,
            mbids, intr, extr, disps, out, ws);
        reduce_kernel<<<1, 256, 0, stream>>>(out, ws);
    }
}